// Round 9
// baseline (225.666 us; speedup 1.0000x reference)
//
#include <hip/hip_runtime.h>
#include <hip/hip_bf16.h>

typedef __attribute__((ext_vector_type(8))) short bf16x8;
typedef __attribute__((ext_vector_type(4))) float f32x4;
typedef __attribute__((ext_vector_type(4))) float fvec4;
typedef __attribute__((ext_vector_type(8))) unsigned short u16x8;

// B=4, T=256, U=64 -> M = 65536 rows; K(J)=512; N(V)=1024

__device__ __forceinline__ unsigned short f2bf(float f) {
  unsigned int u = __builtin_bit_cast(unsigned int, f);
  u += 0x7FFFu + ((u >> 16) & 1u);   // round-to-nearest-even
  return (unsigned short)(u >> 16);
}

__device__ __forceinline__ float fast_tanh(float x) {
  float cx = fminf(fmaxf(x, -9.0f), 9.0f);
  float e2 = __expf(cx + cx);
  return (e2 - 1.0f) * __builtin_amdgcn_rcpf(e2 + 1.0f);
}

// ---- fused prep: enc-proj (blocks 0..127), pred-proj (128..159), W_out^T (160..287)

__device__ __forceinline__ void proj_body(
    const float* __restrict__ x, const float* __restrict__ W,
    const float* __restrict__ bias, float* __restrict__ out,
    int blk, uint8_t* sh) {
  float (*xt)[9] = (float (*)[9])sh;   // [256][9] f32 = 9216 B
  const int tid = threadIdx.x;
  const int row0 = blk << 3;
  #pragma unroll
  for (int i = 0; i < 8; ++i)
    xt[tid][i] = x[(size_t)(row0 + i) * 256 + tid];
  __syncthreads();
  float acc0[8] = {0.f,0.f,0.f,0.f,0.f,0.f,0.f,0.f};
  float acc1[8] = {0.f,0.f,0.f,0.f,0.f,0.f,0.f,0.f};
  #pragma unroll 4
  for (int k = 0; k < 256; ++k) {
    float w0 = W[(size_t)k * 512 + tid];
    float w1 = W[(size_t)k * 512 + tid + 256];
    #pragma unroll
    for (int r = 0; r < 8; ++r) {
      float xv = xt[k][r];
      acc0[r] = fmaf(xv, w0, acc0[r]);
      acc1[r] = fmaf(xv, w1, acc1[r]);
    }
  }
  float b0 = bias[tid], b1 = bias[tid + 256];
  #pragma unroll
  for (int r = 0; r < 8; ++r) {
    out[(size_t)(row0 + r) * 512 + tid]       = acc0[r] + b0;
    out[(size_t)(row0 + r) * 512 + tid + 256] = acc1[r] + b1;
  }
}

// W_out [512 k][1024 n] f32 -> Bt2 K-MAJOR bf16: index =
//   (n>>9)*262144 + (k>>5)*16384 + (n&511)*32 + (k&31)
// -> a register B-frag load (16 n-rows x 8 k) is ONE contiguous 1 KiB segment.
__device__ __forceinline__ void transpose_body(
    const float* __restrict__ W, unsigned short* __restrict__ Bt2,
    int blk, uint8_t* sh) {
  unsigned short (*tile)[65] = (unsigned short (*)[65])sh;  // [64 k][65 n]
  const int k0 = (blk & 7) << 6;
  const int n0 = (blk >> 3) << 6;
  const int tid = threadIdx.x;
  #pragma unroll
  for (int i = 0; i < 16; ++i) {
    int idx = tid + (i << 8);
    int r = idx >> 6, c = idx & 63;        // r = k-off, c = n-off (coalesced read)
    tile[r][c] = f2bf(W[(size_t)(k0 + r) * 1024 + n0 + c]);
  }
  __syncthreads();
  #pragma unroll
  for (int i = 0; i < 16; ++i) {
    int idx = tid + (i << 8);
    int r = idx >> 6, c = idx & 63;        // r = n-off, c = k-off
    int ng = n0 + r, kg = k0 + c;
    size_t dst = ((size_t)(ng >> 9) << 18) + ((size_t)(kg >> 5) << 14)
               + ((ng & 511) << 5) + (kg & 31);
    Bt2[dst] = tile[c][r];
  }
}

__global__ __launch_bounds__(256) void prep_kernel(
    const float* __restrict__ enc, const float* __restrict__ We,
    const float* __restrict__ be, float* __restrict__ encp,
    const float* __restrict__ pred, const float* __restrict__ Wd,
    const float* __restrict__ bd, float* __restrict__ predp,
    const float* __restrict__ Wo, unsigned short* __restrict__ Bt2) {
  __shared__ uint8_t sh[9216];
  const int b = blockIdx.x;
  if (b < 128)       proj_body(enc, We, be, encp, b, sh);
  else if (b < 160)  proj_body(pred, Wd, bd, predp, b - 128, sh);
  else               transpose_body(Wo, Bt2, b - 160, sh);
}

// ---- fused joint+gemm, round 9: BM=256, BN=256, 16 waves (4m x 4n, 64x64 each).
// Changes vs r8 (BM=64):
//  * B L2 traffic /4: (M/BM) x B-bytes = 1 GiB -> 256 MiB.
//  * A (256x512) exceeds LDS -> K-SPLIT: two passes of K=256; A half-tile
//    (256 rows x 256 k, 128 KiB, XOR-swizzled) rebuilt by tanh between passes.
//    B register ping-pong flows ACROSS the rebuild (loads stay in flight).
//  * Epilogue barriers are RAW s_barrier + lgkmcnt(0) ONLY: __syncthreads would
//    drain vmcnt(0), i.e. serialize on completion of prior rounds' global
//    STORES (r6-r8 hidden cost). Two ping-pong epi regions; nontemporal 1 KiB
//    stores are never waited on.
__global__ __launch_bounds__(1024, 4) void fused_gemm(
    const float* __restrict__ encp, const float* __restrict__ predp,
    const unsigned short* __restrict__ Bt2, const float* __restrict__ bout,
    float* __restrict__ out) {
  __shared__ uint8_t lds[133120];   // A-half: [256][256 bf16] swz (128K); epi: 2x[64][260] f32
  const int tid = threadIdx.x;
  const int lane = tid & 63, wid = tid >> 6;
  const int fr = lane & 15, fg = lane >> 4;
  const int wm = wid >> 2, wn = wid & 3;      // 4m x 4n wave grid
  const int b = blockIdx.x;
  const int wg = ((b & 7) << 7) + (b >> 3);   // XCD swizzle, 1024 % 8 == 0 (bijective)
  const int nq = wg >> 8, mt = wg & 255;      // mt inner: XCD keeps one B quarter hot
  const int m0 = mt << 8;
  const int n0 = nq << 8;

  // per-lane B base (K-major): n = n0 + wn*64 + nf*16 + fr; elem index =
  // (n>>9)<<18 | kt<<14 | (n&511)<<5 | fg<<3.  nf step = 1<<9, kt step = 1<<14.
  const unsigned short* Bgl =
      Bt2 + ((size_t)(nq >> 1) << 18) +
      ((((nq & 1) << 8) + (wn << 6) + fr) << 5) + (fg << 3);

  bf16x8 bA[4], bB[4];
  #pragma unroll
  for (int nf = 0; nf < 4; ++nf)      // kt=0 loads issued before first tanh phase
    bA[nf] = *(const bf16x8*)(Bgl + (nf << 9));

  // ---- A half-tile build (pass kp): rows 0..255, local k 0..255 (32 chunks)
  // write at row*512 + ((chunk ^ (row&7))<<4)
  auto build_A = [&](int kp) {
    const int r = tid >> 2, cb = tid & 3;
    const float* erow = encp + (((size_t)(mt << 2) + (r >> 6)) << 9) + (kp << 8);
    const float* prow = predp + (((size_t)((mt >> 6) << 6) + (r & 63)) << 9) + (kp << 8);
    uint8_t* rowbase = lds + (r << 9);
    #pragma unroll
    for (int c8 = 0; c8 < 8; ++c8) {
      int chunk = cb + (c8 << 2);
      int k8 = chunk << 3;
      fvec4 e0 = *(const fvec4*)(erow + k8);
      fvec4 e1 = *(const fvec4*)(erow + k8 + 4);
      fvec4 p0 = *(const fvec4*)(prow + k8);
      fvec4 p1 = *(const fvec4*)(prow + k8 + 4);
      u16x8 o;
      #pragma unroll
      for (int i = 0; i < 4; ++i) o[i]     = f2bf(fast_tanh(e0[i] + p0[i]));
      #pragma unroll
      for (int i = 0; i < 4; ++i) o[i + 4] = f2bf(fast_tanh(e1[i] + p1[i]));
      *(u16x8*)(rowbase + ((chunk ^ (r & 7)) << 4)) = o;
    }
  };

  build_A(0);
  asm volatile("s_waitcnt lgkmcnt(0)" ::: "memory");
  __builtin_amdgcn_s_barrier();

  f32x4 acc[4][4];
  f32x4 zero4 = {0.f, 0.f, 0.f, 0.f};
  #pragma unroll
  for (int i = 0; i < 4; ++i)
    #pragma unroll
    for (int j = 0; j < 4; ++j) acc[i][j] = zero4;

  // A read: row = wm*64+mf*16+fr (512 B stride); chunk = ((ktl<<2)|fg)^(fr&7)
  //       = ((ktl^qh)<<2) | (fg^(fr&3)),  qh = (fr>>2)&1
  const int qh = (fr >> 2) & 1;
  int arow[4];
  #pragma unroll
  for (int mf = 0; mf < 4; ++mf)
    arow[mf] = (((wm << 6) + (mf << 4) + fr) << 9) + ((fg ^ (fr & 3)) << 4);

  // one K-step (global kt): prefetch B(kt+1), read A frags (local ktl), 16 MFMA
  auto step = [&](int kt, bf16x8 (&cur)[4], bf16x8 (&nxt)[4]) {
    const int ktn = kt < 15 ? kt + 1 : 15;   // last iter: harmless dup reload
    #pragma unroll
    for (int nf = 0; nf < 4; ++nf)
      nxt[nf] = *(const bf16x8*)(Bgl + ((size_t)ktn << 14) + (nf << 9));
    const int ko = ((kt & 7) ^ qh) << 6;
    bf16x8 af[4];
    #pragma unroll
    for (int mf = 0; mf < 4; ++mf)
      af[mf] = *(const bf16x8*)(lds + arow[mf] + ko);
    #pragma unroll
    for (int mf = 0; mf < 4; ++mf)
      #pragma unroll
      for (int nf = 0; nf < 4; ++nf)
        acc[mf][nf] = __builtin_amdgcn_mfma_f32_16x16x32_bf16(cur[nf], af[mf],
                                                              acc[mf][nf], 0, 0, 0);
  };

  // pass 0: kt 0..7
  #pragma unroll
  for (int kt = 0; kt < 8; kt += 2) {
    step(kt,     bA, bB);
    step(kt + 1, bB, bA);
  }
  // rebuild A for K-half 1.  lgkm-only barrier: all waves' kt=7 ds_reads done;
  // B(8)/B(9) prefetch stays in flight, tanh covers its latency.
  asm volatile("s_waitcnt lgkmcnt(0)" ::: "memory");
  __builtin_amdgcn_s_barrier();
  build_A(1);
  asm volatile("s_waitcnt lgkmcnt(0)" ::: "memory");
  __builtin_amdgcn_s_barrier();
  // pass 1: kt 8..15 (parity continues: 8 even -> bA is cur)
  #pragma unroll
  for (int kt = 8; kt < 16; kt += 2) {
    step(kt,     bA, bB);
    step(kt + 1, bB, bA);
  }

  // ---- epilogue: 2 ping-pong epi regions [64][260] f32; raw barriers only
  // (no vmcnt drain -> stores from prior rounds never block).
  const int colw = (wn << 6) + (fg << 2);
  fvec4 bvv[4];
  #pragma unroll
  for (int nf = 0; nf < 4; ++nf)
    bvv[nf] = *(const fvec4*)&bout[n0 + colw + (nf << 4)];

  const int er_dep = (wm << 4) + fr;   // deposit row 0..63
  #pragma unroll
  for (int mf = 0; mf < 4; ++mf) {
    float* ep = (float*)(lds + (mf & 1) * 66560);
    asm volatile("s_waitcnt lgkmcnt(0)" ::: "memory");
    __builtin_amdgcn_s_barrier();      // region free (drained 2 rounds ago) / A dead
    #pragma unroll
    for (int nf = 0; nf < 4; ++nf) {
      fvec4 o = acc[mf][nf] + bvv[nf];
      *(fvec4*)&ep[er_dep * 260 + colw + (nf << 4)] = o;
    }
    asm volatile("s_waitcnt lgkmcnt(0)" ::: "memory");
    __builtin_amdgcn_s_barrier();      // deposits visible
    #pragma unroll
    for (int j = 0; j < 4; ++j) {
      const int er = (wid << 2) + j;   // one full 256-col row per instr (1 KiB)
      fvec4 v = *(const fvec4*)&ep[er * 260 + (lane << 2)];
      const int gm = m0 + ((er >> 4) << 6) + (mf << 4) + (er & 15);
      __builtin_nontemporal_store(
          v, (fvec4*)&out[(size_t)gm * 1024 + n0 + (lane << 2)]);
    }
  }
}

extern "C" void kernel_launch(void* const* d_in, const int* in_sizes, int n_in,
                              void* d_out, int out_size, void* d_ws, size_t ws_size,
                              hipStream_t stream) {
  const float* enc   = (const float*)d_in[0];
  const float* pred  = (const float*)d_in[1];
  const float* W_enc = (const float*)d_in[2];
  const float* b_enc = (const float*)d_in[3];
  const float* W_dec = (const float*)d_in[4];
  const float* b_dec = (const float*)d_in[5];
  const float* W_out = (const float*)d_in[6];
  const float* b_out = (const float*)d_in[7];
  float* out = (float*)d_out;

  uint8_t* ws = (uint8_t*)d_ws;
  float* encp  = (float*)ws;                           // [1024][512] f32, 2 MiB
  float* predp = (float*)(ws + 2097152);               // [256][512]  f32, 0.5 MiB
  unsigned short* bt2 = (unsigned short*)(ws + 2621440);// K-major W_out^T bf16, 1 MiB

  prep_kernel<<<288, 256, 0, stream>>>(enc, W_enc, b_enc, encp,
                                       pred, W_dec, b_dec, predp,
                                       W_out, bt2);
  fused_gemm<<<1024, 1024, 0, stream>>>(encp, predp, bt2, b_out, out);
}

// Round 10
// 125.219 us; speedup vs baseline: 1.8022x; 1.8022x over previous
//
#include <hip/hip_runtime.h>
#include <hip/hip_bf16.h>

typedef __attribute__((ext_vector_type(8))) short bf16x8;
typedef __attribute__((ext_vector_type(4))) float f32x4;
typedef __attribute__((ext_vector_type(4))) float fvec4;
typedef __attribute__((ext_vector_type(8))) unsigned short u16x8;

// B=4, T=256, U=64 -> M = 65536 rows; K(J)=512; N(V)=1024

__device__ __forceinline__ unsigned short f2bf(float f) {
  unsigned int u = __builtin_bit_cast(unsigned int, f);
  u += 0x7FFFu + ((u >> 16) & 1u);   // round-to-nearest-even
  return (unsigned short)(u >> 16);
}

__device__ __forceinline__ float fast_tanh(float x) {
  float cx = fminf(fmaxf(x, -9.0f), 9.0f);
  float e2 = __expf(cx + cx);
  return (e2 - 1.0f) * __builtin_amdgcn_rcpf(e2 + 1.0f);
}

// ---- fused prep: enc-proj (blocks 0..127), pred-proj (128..159), W_out^T (160..287)

__device__ __forceinline__ void proj_body(
    const float* __restrict__ x, const float* __restrict__ W,
    const float* __restrict__ bias, float* __restrict__ out,
    int blk, uint8_t* sh) {
  float (*xt)[9] = (float (*)[9])sh;   // [256][9] f32 = 9216 B
  const int tid = threadIdx.x;
  const int row0 = blk << 3;
  #pragma unroll
  for (int i = 0; i < 8; ++i)
    xt[tid][i] = x[(size_t)(row0 + i) * 256 + tid];
  __syncthreads();
  float acc0[8] = {0.f,0.f,0.f,0.f,0.f,0.f,0.f,0.f};
  float acc1[8] = {0.f,0.f,0.f,0.f,0.f,0.f,0.f,0.f};
  #pragma unroll 4
  for (int k = 0; k < 256; ++k) {
    float w0 = W[(size_t)k * 512 + tid];
    float w1 = W[(size_t)k * 512 + tid + 256];
    #pragma unroll
    for (int r = 0; r < 8; ++r) {
      float xv = xt[k][r];
      acc0[r] = fmaf(xv, w0, acc0[r]);
      acc1[r] = fmaf(xv, w1, acc1[r]);
    }
  }
  float b0 = bias[tid], b1 = bias[tid + 256];
  #pragma unroll
  for (int r = 0; r < 8; ++r) {
    out[(size_t)(row0 + r) * 512 + tid]       = acc0[r] + b0;
    out[(size_t)(row0 + r) * 512 + tid + 256] = acc1[r] + b1;
  }
}

// W_out [512 k][1024 n] f32 -> Bt2 K-MAJOR bf16: index =
//   (n>>9)*262144 + (k>>5)*16384 + (n&511)*32 + (k&31)
// -> a register B-frag load (16 n-rows x 8 k) is ONE contiguous 1 KiB segment.
__device__ __forceinline__ void transpose_body(
    const float* __restrict__ W, unsigned short* __restrict__ Bt2,
    int blk, uint8_t* sh) {
  unsigned short (*tile)[65] = (unsigned short (*)[65])sh;  // [64 k][65 n]
  const int k0 = (blk & 7) << 6;
  const int n0 = (blk >> 3) << 6;
  const int tid = threadIdx.x;
  #pragma unroll
  for (int i = 0; i < 16; ++i) {
    int idx = tid + (i << 8);
    int r = idx >> 6, c = idx & 63;        // r = k-off, c = n-off (coalesced read)
    tile[r][c] = f2bf(W[(size_t)(k0 + r) * 1024 + n0 + c]);
  }
  __syncthreads();
  #pragma unroll
  for (int i = 0; i < 16; ++i) {
    int idx = tid + (i << 8);
    int r = idx >> 6, c = idx & 63;        // r = n-off, c = k-off
    int ng = n0 + r, kg = k0 + c;
    size_t dst = ((size_t)(ng >> 9) << 18) + ((size_t)(kg >> 5) << 14)
               + ((ng & 511) << 5) + (kg & 31);
    Bt2[dst] = tile[c][r];
  }
}

__global__ __launch_bounds__(256) void prep_kernel(
    const float* __restrict__ enc, const float* __restrict__ We,
    const float* __restrict__ be, float* __restrict__ encp,
    const float* __restrict__ pred, const float* __restrict__ Wd,
    const float* __restrict__ bd, float* __restrict__ predp,
    const float* __restrict__ Wo, unsigned short* __restrict__ Bt2) {
  __shared__ uint8_t sh[9216];
  const int b = blockIdx.x;
  if (b < 128)       proj_body(enc, We, be, encp, b, sh);
  else if (b < 160)  proj_body(pred, Wd, bd, predp, b - 128, sh);
  else               transpose_body(Wo, Bt2, b - 160, sh);
}

// ---- fused joint+gemm (r8 structure, r10 epilogue):
// BM=64, BN=512, K=512, 8 waves x (64M x 64N), 2 blocks/CU.
//  * A = bf16(tanh(encp+predp)) once into 64 KiB XOR-swizzled LDS -> K-loop has
//    ZERO barriers (A read-only; B never touches LDS).
//  * B-frags DIRECT to registers from K-major Bt2 (contiguous 1 KiB/load),
//    register ping-pong prefetch depth 1.
//  * r10 CHANGE: epilogue never drains vmcnt. __syncthreads() emits
//    s_waitcnt vmcnt(0) -> each round waited for the PREVIOUS round's global
//    stores to hit HBM (8 drains/block, serializing both resident blocks).
//    Now: 2 ping-pong epi regions + raw s_barrier + lgkmcnt(0) only; the
//    nontemporal 1 KiB stores are fire-and-forget.
__global__ __launch_bounds__(512, 4) void fused_gemm(
    const float* __restrict__ encp, const float* __restrict__ predp,
    const unsigned short* __restrict__ Bt2, const float* __restrict__ bout,
    float* __restrict__ out) {
  __shared__ uint8_t lds[66560];   // A: [64][512 bf16] swz (64K); epi: 2x[16][516] f32
  const int tid = threadIdx.x;
  const int lane = tid & 63, wid = tid >> 6;
  const int fr = lane & 15, fg = lane >> 4;
  const int b = blockIdx.x;
  const int wg = ((b & 7) << 8) + (b >> 3);   // XCD swizzle, 2048 % 8 == 0 (bijective)
  const int mt = wg >> 1, half = wg & 1;      // half inner: pair shares encp row
  const int m0 = mt << 6;
  const int cb0 = half << 9;

  // per-lane B base in K-major layout: elem = (kt<<14) + (n<<5) + (fg<<3),
  // n = wid*64 + nf*16 + fr.  frag nf offset = nf<<9; kt offset = kt<<14.
  const unsigned short* Bgl =
      Bt2 + ((size_t)half << 18) + (((wid << 6) + fr) << 5) + (fg << 3);

  bf16x8 bA[4], bB[4];
  #pragma unroll
  for (int nf = 0; nf < 4; ++nf)      // issue tile-0 B loads before tanh phase
    bA[nf] = *(const bf16x8*)(Bgl + (nf << 9));

  // ---- phase 0: A tile -> swizzled LDS.  f(row,chunk) = row*1024 + ((chunk^(row&7))<<4)
  {
    const int r = tid >> 3, cb = tid & 7;
    const float* erow = encp + ((size_t)mt << 9);
    const float* prow = predp + ((size_t)(((mt >> 8) << 6) + r) << 9);
    uint8_t* rowbase = lds + (r << 10);
    #pragma unroll
    for (int c8 = 0; c8 < 8; ++c8) {
      int chunk = cb + (c8 << 3);
      int k8 = chunk << 3;
      fvec4 e0 = *(const fvec4*)(erow + k8);
      fvec4 e1 = *(const fvec4*)(erow + k8 + 4);
      fvec4 p0 = *(const fvec4*)(prow + k8);
      fvec4 p1 = *(const fvec4*)(prow + k8 + 4);
      u16x8 o;
      #pragma unroll
      for (int i = 0; i < 4; ++i) o[i]     = f2bf(fast_tanh(e0[i] + p0[i]));
      #pragma unroll
      for (int i = 0; i < 4; ++i) o[i + 4] = f2bf(fast_tanh(e1[i] + p1[i]));
      *(u16x8*)(rowbase + ((chunk ^ (r & 7)) << 4)) = o;
    }
  }
  asm volatile("s_waitcnt lgkmcnt(0)" ::: "memory");
  __builtin_amdgcn_s_barrier();   // A published; K-loop below is barrier-free

  f32x4 acc[4][4];
  f32x4 zero4 = {0.f, 0.f, 0.f, 0.f};
  #pragma unroll
  for (int i = 0; i < 4; ++i)
    #pragma unroll
    for (int j = 0; j < 4; ++j) acc[i][j] = zero4;

  // A read addr: chunk = ((kt<<2)|fg) ^ (fr&7) = ((kt^qh)<<2) | (fg^(fr&3))
  const int qh = (fr >> 2) & 1;
  int arow[4];
  #pragma unroll
  for (int mf = 0; mf < 4; ++mf)
    arow[mf] = ((((mf << 4) + fr)) << 10) + ((fg ^ (fr & 3)) << 4);

  // one K-step: prefetch B(kt+1) into nxt (contiguous 1KiB/instr), read A frags
  // from LDS, 16 MFMA on cur.  No barriers, no LDS writes.
  auto step = [&](int kt, bf16x8 (&cur)[4], bf16x8 (&nxt)[4]) {
    const int ktn = kt < 15 ? kt + 1 : 15;   // last iter: harmless dup reload
    #pragma unroll
    for (int nf = 0; nf < 4; ++nf)
      nxt[nf] = *(const bf16x8*)(Bgl + (ktn << 14) + (nf << 9));
    const int ko = (kt ^ qh) << 6;
    bf16x8 af[4];
    #pragma unroll
    for (int mf = 0; mf < 4; ++mf)
      af[mf] = *(const bf16x8*)(lds + arow[mf] + ko);
    #pragma unroll
    for (int mf = 0; mf < 4; ++mf)
      #pragma unroll
      for (int nf = 0; nf < 4; ++nf)
        acc[mf][nf] = __builtin_amdgcn_mfma_f32_16x16x32_bf16(cur[nf], af[mf],
                                                              acc[mf][nf], 0, 0, 0);
  };

  #pragma unroll
  for (int kt = 0; kt < 16; kt += 2) {   // static ping-pong (rule #20)
    step(kt,     bA, bB);
    step(kt + 1, bB, bA);
  }

  // ---- epilogue: ping-pong LDS re-layout, NO vmcnt drains.
  // Region r (33024 B) = [16][516] f32.  Per mf round:
  //   lgkm+barrier (region's old readers done; first rounds: K-loop reads done)
  //   deposit acc+bias -> region   (ds_write)
  //   lgkm+barrier (deposits visible)
  //   stream rows out as contiguous 1 KiB nontemporal stores (never waited).
  const int colw = (wid << 6) + (fg << 2);
  fvec4 bvv[4];
  #pragma unroll
  for (int nf = 0; nf < 4; ++nf)
    bvv[nf] = *(const fvec4*)&bout[cb0 + colw + (nf << 4)];

  #pragma unroll
  for (int mf = 0; mf < 4; ++mf) {
    float* ep = (float*)(lds + (mf & 1) * 33024);
    asm volatile("s_waitcnt lgkmcnt(0)" ::: "memory");
    __builtin_amdgcn_s_barrier();
    #pragma unroll
    for (int nf = 0; nf < 4; ++nf) {
      fvec4 o = acc[mf][nf] + bvv[nf];
      *(fvec4*)&ep[fr * 516 + colw + (nf << 4)] = o;
    }
    asm volatile("s_waitcnt lgkmcnt(0)" ::: "memory");
    __builtin_amdgcn_s_barrier();
    #pragma unroll
    for (int j = 0; j < 4; ++j) {
      const int idx = (wid << 2) + j;
      const int row = idx >> 1, seg = idx & 1;
      fvec4 v = *(const fvec4*)&ep[row * 516 + (seg << 8) + (lane << 2)];
      __builtin_nontemporal_store(
          v, (fvec4*)&out[(size_t)(m0 + (mf << 4) + row) * 1024 + cb0 +
                          (seg << 8) + (lane << 2)]);
    }
  }
}

extern "C" void kernel_launch(void* const* d_in, const int* in_sizes, int n_in,
                              void* d_out, int out_size, void* d_ws, size_t ws_size,
                              hipStream_t stream) {
  const float* enc   = (const float*)d_in[0];
  const float* pred  = (const float*)d_in[1];
  const float* W_enc = (const float*)d_in[2];
  const float* b_enc = (const float*)d_in[3];
  const float* W_dec = (const float*)d_in[4];
  const float* b_dec = (const float*)d_in[5];
  const float* W_out = (const float*)d_in[6];
  const float* b_out = (const float*)d_in[7];
  float* out = (float*)d_out;

  uint8_t* ws = (uint8_t*)d_ws;
  float* encp  = (float*)ws;                           // [1024][512] f32, 2 MiB
  float* predp = (float*)(ws + 2097152);               // [256][512]  f32, 0.5 MiB
  unsigned short* bt2 = (unsigned short*)(ws + 2621440);// K-major W_out^T bf16, 1 MiB

  prep_kernel<<<288, 256, 0, stream>>>(enc, W_enc, b_enc, encp,
                                       pred, W_dec, b_dec, predp,
                                       W_out, bt2);
  fused_gemm<<<2048, 512, 0, stream>>>(encp, predp, bt2, b_out, out);
}